// Round 1
// baseline (525.332 us; speedup 1.0000x reference)
//
#include <hip/hip_runtime.h>
#include <hip/hip_bf16.h>
#include <math.h>

#define EMBED 1024
#define HIDDEN 128
#define NPROTO 512

typedef short bf16x8 __attribute__((ext_vector_type(8)));
typedef short bf16x4 __attribute__((ext_vector_type(4)));
typedef float f32x4 __attribute__((ext_vector_type(4)));

__device__ __forceinline__ unsigned short f2bf(float x) {
    unsigned u = __builtin_bit_cast(unsigned, x);
    unsigned r = u + 0x7FFFu + ((u >> 16) & 1u);   // round-to-nearest-even
    return (unsigned short)(r >> 16);
}

// Prep: blocks 0..63 compute proto_h = prototypes @ W1[1024:2048]  (fp32)
//       blocks 64..127 convert W1[0:1024] -> bf16, transposed [n][k]
__global__ __launch_bounds__(128) void prep_kernel(
    const float* __restrict__ prototypes,   // [512][1024]
    const float* __restrict__ W1,           // [2048][128]
    float* __restrict__ proto_h,            // ws [512][128]
    unsigned short* __restrict__ w1t)       // ws [128][1024] bf16
{
    int blk = blockIdx.x;
    int t = threadIdx.x;
    if (blk < 64) {
        __shared__ float pl[8][1024];
        int p0 = blk * 8;
        const float4* src = (const float4*)(prototypes + (size_t)p0 * EMBED);
        float4* dst = (float4*)(&pl[0][0]);
        #pragma unroll
        for (int i = 0; i < 16; ++i) dst[t + i * 128] = src[t + i * 128];
        __syncthreads();
        float acc[8] = {0.f,0.f,0.f,0.f,0.f,0.f,0.f,0.f};
        for (int k = 0; k < 1024; k += 8) {
            float w[8];
            #pragma unroll
            for (int j = 0; j < 8; ++j) w[j] = W1[(size_t)(1024 + k + j) * 128 + t];
            #pragma unroll
            for (int j = 0; j < 8; ++j) {
                #pragma unroll
                for (int p = 0; p < 8; ++p) acc[p] += pl[p][k + j] * w[j];
            }
        }
        #pragma unroll
        for (int p = 0; p < 8; ++p) proto_h[(size_t)(p0 + p) * 128 + t] = acc[p];
    } else {
        int b = blk - 64;
        #pragma unroll
        for (int i = 0; i < 16; ++i) {
            int flat = b * 2048 + i * 128 + t;   // 0..131071
            int k = flat >> 7;
            int n = flat & 127;
            w1t[(size_t)n * 1024 + k] = f2bf(W1[(size_t)k * 128 + n]);
        }
    }
}

// Fused: argmin(distances) -> q@W1_top (bf16 MFMA) + proto_h[idx] + b1
//        -> relu -> dot W2 -> sigmoid
__global__ __launch_bounds__(256) void main_kernel(
    const float* __restrict__ qf,           // [65536][1024]
    const float* __restrict__ dist,         // [65536][512]
    const float* __restrict__ b1,           // [128]
    const float* __restrict__ W2,           // [128]
    const float* __restrict__ b2,           // [1]
    const float* __restrict__ proto_h,      // [512][128]
    const unsigned short* __restrict__ w1t, // [128][1024] bf16
    float* __restrict__ out)                // [65536]
{
    const int LDA = 72;  // 64 + 8 pad: frag-read row stride 144B -> 2-way banks (free)
    __shared__ unsigned short a_lds[128 * 72];
    __shared__ unsigned short b_lds[128 * 72];
    __shared__ int s_idx[128];
    __shared__ float s_red[128][2];

    int t = threadIdx.x;
    int wave = t >> 6, lane = t & 63;
    int blk = blockIdx.x;
    int q0 = blk * 128;

    // ---- Phase 1: argmin over 512 distances; wave w handles queries w*32..w*32+31
    for (int i = 0; i < 32; ++i) {
        int q = wave * 32 + i;
        const float* dr = dist + (size_t)(q0 + q) * 512;
        float4 v0 = ((const float4*)dr)[lane];
        float4 v1 = ((const float4*)dr)[lane + 64];
        float bv = v0.x; int bi = lane * 4;
        if (v0.y < bv) { bv = v0.y; bi = lane * 4 + 1; }
        if (v0.z < bv) { bv = v0.z; bi = lane * 4 + 2; }
        if (v0.w < bv) { bv = v0.w; bi = lane * 4 + 3; }
        int b1i = 256 + lane * 4;
        if (v1.x < bv) { bv = v1.x; bi = b1i; }
        if (v1.y < bv) { bv = v1.y; bi = b1i + 1; }
        if (v1.z < bv) { bv = v1.z; bi = b1i + 2; }
        if (v1.w < bv) { bv = v1.w; bi = b1i + 3; }
        #pragma unroll
        for (int s = 1; s < 64; s <<= 1) {
            float ov = __shfl_xor(bv, s);
            int   oi = __shfl_xor(bi, s);
            if (ov < bv || (ov == bv && oi < bi)) { bv = ov; bi = oi; }
        }
        if (lane == 0) s_idx[q] = bi;
    }

    // ---- Phase 2: 128x128 MFMA tile over K=1024, BK=64
    int wave_m = wave >> 1, wave_n = wave & 1;
    int quad = lane >> 4, tid16 = lane & 15;
    f32x4 acc[4][4];
    #pragma unroll
    for (int mi = 0; mi < 4; ++mi)
        #pragma unroll
        for (int ni = 0; ni < 4; ++ni)
            acc[mi][ni] = (f32x4){0.f, 0.f, 0.f, 0.f};

    for (int kt = 0; kt < 1024; kt += 64) {
        // stage A: 128 rows x 64 k, fp32 -> bf16
        #pragma unroll
        for (int i = 0; i < 8; ++i) {
            int m = (t >> 4) + i * 16;
            int k = (t & 15) * 4;
            float4 v = *(const float4*)(qf + (size_t)(q0 + m) * 1024 + kt + k);
            bf16x4 pk;
            pk.x = (short)f2bf(v.x); pk.y = (short)f2bf(v.y);
            pk.z = (short)f2bf(v.z); pk.w = (short)f2bf(v.w);
            *(bf16x4*)(&a_lds[m * LDA + k]) = pk;
        }
        // stage B: 128 n-rows x 64 k (already bf16, [n][k] layout)
        #pragma unroll
        for (int i = 0; i < 4; ++i) {
            int n = (t >> 3) + i * 32;
            int k = (t & 7) * 8;
            bf16x8 v = *(const bf16x8*)(w1t + (size_t)n * 1024 + kt + k);
            *(bf16x8*)(&b_lds[n * LDA + k]) = v;
        }
        __syncthreads();

        #pragma unroll
        for (int ks = 0; ks < 2; ++ks) {
            int kk = ks * 32 + quad * 8;
            bf16x8 af[4], bfr[4];
            #pragma unroll
            for (int mi = 0; mi < 4; ++mi)
                af[mi] = *(bf16x8*)(&a_lds[(wave_m * 64 + mi * 16 + tid16) * LDA + kk]);
            #pragma unroll
            for (int ni = 0; ni < 4; ++ni)
                bfr[ni] = *(bf16x8*)(&b_lds[(wave_n * 64 + ni * 16 + tid16) * LDA + kk]);
            #pragma unroll
            for (int mi = 0; mi < 4; ++mi)
                #pragma unroll
                for (int ni = 0; ni < 4; ++ni)
                    acc[mi][ni] = __builtin_amdgcn_mfma_f32_16x16x32_bf16(
                        af[mi], bfr[ni], acc[mi][ni], 0, 0, 0);
        }
        __syncthreads();
    }

    // ---- Epilogue: + b1 + proto_h[idx], relu, * W2, reduce over n, sigmoid
    float b1v[4], w2v[4];
    #pragma unroll
    for (int ni = 0; ni < 4; ++ni) {
        int n = wave_n * 64 + ni * 16 + tid16;
        b1v[ni] = b1[n];
        w2v[ni] = W2[n];
    }
    #pragma unroll
    for (int mi = 0; mi < 4; ++mi) {
        #pragma unroll
        for (int r = 0; r < 4; ++r) {
            int m = wave_m * 64 + mi * 16 + quad * 4 + r;
            const float* ph = proto_h + (size_t)s_idx[m] * 128;
            float sum = 0.f;
            #pragma unroll
            for (int ni = 0; ni < 4; ++ni) {
                int n = wave_n * 64 + ni * 16 + tid16;
                float v = acc[mi][ni][r] + b1v[ni] + ph[n];
                sum += fmaxf(v, 0.f) * w2v[ni];
            }
            #pragma unroll
            for (int s = 1; s < 16; s <<= 1) sum += __shfl_xor(sum, s);
            if (tid16 == 0) s_red[m][wave_n] = sum;
        }
    }
    __syncthreads();
    if (t < 128) {
        float s = s_red[t][0] + s_red[t][1] + b2[0];
        out[q0 + t] = 1.f / (1.f + expf(-s));
    }
}

extern "C" void kernel_launch(void* const* d_in, const int* in_sizes, int n_in,
                              void* d_out, int out_size, void* d_ws, size_t ws_size,
                              hipStream_t stream) {
    const float* qf    = (const float*)d_in[0];   // [65536,1024]
    const float* proto = (const float*)d_in[1];   // [512,1024]
    const float* dist  = (const float*)d_in[2];   // [65536,512]
    const float* W1    = (const float*)d_in[3];   // [2048,128]
    const float* b1    = (const float*)d_in[4];   // [128]
    const float* W2    = (const float*)d_in[5];   // [128,1]
    const float* b2    = (const float*)d_in[6];   // [1]
    float* out = (float*)d_out;

    float* proto_h = (float*)d_ws;                         // 512*128*4 = 256 KB
    unsigned short* w1t = (unsigned short*)((char*)d_ws + 512 * 128 * 4); // 256 KB

    prep_kernel<<<128, 128, 0, stream>>>(proto, W1, proto_h, w1t);

    int nq = in_sizes[0] / EMBED;  // 65536
    main_kernel<<<nq / 128, 256, 0, stream>>>(qf, dist, b1, W2, b2, proto_h, w1t, out);
}

// Round 2
// 504.093 us; speedup vs baseline: 1.0421x; 1.0421x over previous
//
#include <hip/hip_runtime.h>
#include <hip/hip_bf16.h>
#include <math.h>

#define EMBED 1024
#define HIDDEN 128
#define NPROTO 512
#define LDA 72   // 64 + 8 pad: frag-read row stride 144B -> 2-way bank alias (free)

typedef short bf16x8 __attribute__((ext_vector_type(8)));
typedef float f32x4 __attribute__((ext_vector_type(4)));

__device__ __forceinline__ unsigned short f2bf(float x) {
    unsigned u = __builtin_bit_cast(unsigned, x);
    unsigned r = u + 0x7FFFu + ((u >> 16) & 1u);   // round-to-nearest-even
    return (unsigned short)(r >> 16);
}

// Prep: blocks 0..255  -> proto_h[2b], proto_h[2b+1]  (fp32 GEMV, K=1024)
//       blocks 256..319 -> w1t = bf16(W1[0:1024])^T, [n][k] layout, bf16x8 writes
__global__ __launch_bounds__(256) void prep_kernel(
    const float* __restrict__ prototypes,   // [512][1024]
    const float* __restrict__ W1,           // [2048][128]
    float* __restrict__ proto_h,            // ws [512][128]
    unsigned short* __restrict__ w1t)       // ws [128][1024] bf16
{
    int b = blockIdx.x;
    int t = threadIdx.x;
    if (b < 256) {
        int ph = t >> 7, h = t & 127;
        int p = b * 2 + ph;
        const float* pr = prototypes + (size_t)p * EMBED;
        const float* w  = W1 + (size_t)EMBED * HIDDEN + h;   // W1 bottom half, col h
        float acc = 0.f;
        for (int k = 0; k < EMBED; k += 8) {
            #pragma unroll
            for (int j = 0; j < 8; ++j)
                acc += pr[k + j] * w[(size_t)(k + j) * HIDDEN];
        }
        proto_h[(size_t)p * HIDDEN + h] = acc;
    } else {
        int s = (b - 256) * 256 + t;        // 0..16383
        int n = s & 127;
        int k0 = (s >> 7) * 8;              // 0..1016
        bf16x8 v;
        #pragma unroll
        for (int j = 0; j < 8; ++j)
            v[j] = (short)f2bf(W1[(size_t)(k0 + j) * HIDDEN + n]);
        *(bf16x8*)(w1t + (size_t)n * EMBED + k0) = v;
    }
}

// Fused: argmin(distances) -> q@W1_top (bf16 MFMA, dbuf LDS A, global-direct B)
//        + proto_h[idx] + b1 -> relu -> dot W2 -> sigmoid
__global__ __launch_bounds__(256, 3) void main_kernel(
    const float* __restrict__ qf,           // [65536][1024]
    const float* __restrict__ dist,         // [65536][512]
    const float* __restrict__ b1,           // [128]
    const float* __restrict__ W2,           // [128]
    const float* __restrict__ b2,           // [1]
    const float* __restrict__ proto_h,      // [512][128]
    const unsigned short* __restrict__ w1t, // [128][1024] bf16
    float* __restrict__ out)                // [65536]
{
    __shared__ unsigned short a_lds[2][128 * LDA];
    __shared__ int s_idx[128];
    __shared__ float s_red[128][2];

    int t = threadIdx.x;
    int wave = t >> 6, lane = t & 63;
    int q0 = blockIdx.x * 128;

    // Staging slot mapping: slot i (0..3): row m, 8-wide k chunk
    int sm = t >> 3;            // 0..31 (+ i*32)
    int sk = (t & 7) * 8;       // 0..56

    // ---- Issue tile-0 A loads (HBM latency overlaps the whole argmin phase)
    float4 pre[4][2];
    {
        const float* base = qf + (size_t)q0 * EMBED;
        #pragma unroll
        for (int i = 0; i < 4; ++i) {
            const float* src = base + (size_t)(sm + i * 32) * EMBED + sk;
            pre[i][0] = *(const float4*)src;
            pre[i][1] = *(const float4*)(src + 4);
        }
    }

    // ---- Phase 1: argmin over 512 distances; wave w: queries w*32..w*32+31,
    //      4-way unrolled so the 6-step shuffle chains interleave.
    for (int i = 0; i < 32; i += 4) {
        float4 v0[4], v1[4];
        #pragma unroll
        for (int j = 0; j < 4; ++j) {
            const float* dr = dist + (size_t)(q0 + wave * 32 + i + j) * NPROTO;
            v0[j] = ((const float4*)dr)[lane];
            v1[j] = ((const float4*)dr)[lane + 64];
        }
        #pragma unroll
        for (int j = 0; j < 4; ++j) {
            float bv = v0[j].x; int bi = lane * 4;
            if (v0[j].y < bv) { bv = v0[j].y; bi = lane * 4 + 1; }
            if (v0[j].z < bv) { bv = v0[j].z; bi = lane * 4 + 2; }
            if (v0[j].w < bv) { bv = v0[j].w; bi = lane * 4 + 3; }
            int c = 256 + lane * 4;
            if (v1[j].x < bv) { bv = v1[j].x; bi = c; }
            if (v1[j].y < bv) { bv = v1[j].y; bi = c + 1; }
            if (v1[j].z < bv) { bv = v1[j].z; bi = c + 2; }
            if (v1[j].w < bv) { bv = v1[j].w; bi = c + 3; }
            #pragma unroll
            for (int s = 1; s < 64; s <<= 1) {
                float ov = __shfl_xor(bv, s);
                int   oi = __shfl_xor(bi, s);
                if (ov < bv || (ov == bv && oi < bi)) { bv = ov; bi = oi; }
            }
            if (lane == 0) s_idx[wave * 32 + i + j] = bi;
        }
    }

    // ---- Write tile 0 into buffer 0
    #pragma unroll
    for (int i = 0; i < 4; ++i) {
        bf16x8 pk;
        pk[0] = (short)f2bf(pre[i][0].x); pk[1] = (short)f2bf(pre[i][0].y);
        pk[2] = (short)f2bf(pre[i][0].z); pk[3] = (short)f2bf(pre[i][0].w);
        pk[4] = (short)f2bf(pre[i][1].x); pk[5] = (short)f2bf(pre[i][1].y);
        pk[6] = (short)f2bf(pre[i][1].z); pk[7] = (short)f2bf(pre[i][1].w);
        *(bf16x8*)(&a_lds[0][(sm + i * 32) * LDA + sk]) = pk;
    }
    __syncthreads();

    // ---- Phase 2: 128x128 MFMA over K=1024, BK=64, dbuf A, global-direct B
    int wave_m = wave >> 1, wave_n = wave & 1;
    int quad = lane >> 4, tid16 = lane & 15;
    f32x4 acc[4][4];
    #pragma unroll
    for (int mi = 0; mi < 4; ++mi)
        #pragma unroll
        for (int ni = 0; ni < 4; ++ni)
            acc[mi][ni] = (f32x4){0.f, 0.f, 0.f, 0.f};

    for (int kt = 0; kt < EMBED; kt += 64) {
        int cur = (kt >> 6) & 1;
        bool more = (kt + 64) < EMBED;

        // B fragments straight from global (w1t is 256 KB, L2-resident)
        bf16x8 bfr[2][4];
        #pragma unroll
        for (int ks = 0; ks < 2; ++ks)
            #pragma unroll
            for (int ni = 0; ni < 4; ++ni)
                bfr[ks][ni] = *(const bf16x8*)(
                    w1t + (size_t)(wave_n * 64 + ni * 16 + tid16) * EMBED
                        + kt + ks * 32 + quad * 8);

        // Prefetch next A tile (HBM) — overlaps this tile's MFMA
        if (more) {
            const float* base = qf + (size_t)q0 * EMBED + kt + 64;
            #pragma unroll
            for (int i = 0; i < 4; ++i) {
                const float* src = base + (size_t)(sm + i * 32) * EMBED + sk;
                pre[i][0] = *(const float4*)src;
                pre[i][1] = *(const float4*)(src + 4);
            }
        }

        // Compute on current buffer
        #pragma unroll
        for (int ks = 0; ks < 2; ++ks) {
            int kk = ks * 32 + quad * 8;
            bf16x8 af[4];
            #pragma unroll
            for (int mi = 0; mi < 4; ++mi)
                af[mi] = *(bf16x8*)(&a_lds[cur][(wave_m * 64 + mi * 16 + tid16) * LDA + kk]);
            #pragma unroll
            for (int mi = 0; mi < 4; ++mi)
                #pragma unroll
                for (int ni = 0; ni < 4; ++ni)
                    acc[mi][ni] = __builtin_amdgcn_mfma_f32_16x16x32_bf16(
                        af[mi], bfr[ks][ni], acc[mi][ni], 0, 0, 0);
        }

        // Convert + write next tile into the other buffer
        if (more) {
            #pragma unroll
            for (int i = 0; i < 4; ++i) {
                bf16x8 pk;
                pk[0] = (short)f2bf(pre[i][0].x); pk[1] = (short)f2bf(pre[i][0].y);
                pk[2] = (short)f2bf(pre[i][0].z); pk[3] = (short)f2bf(pre[i][0].w);
                pk[4] = (short)f2bf(pre[i][1].x); pk[5] = (short)f2bf(pre[i][1].y);
                pk[6] = (short)f2bf(pre[i][1].z); pk[7] = (short)f2bf(pre[i][1].w);
                *(bf16x8*)(&a_lds[cur ^ 1][(sm + i * 32) * LDA + sk]) = pk;
            }
        }
        __syncthreads();
    }

    // ---- Epilogue: + b1 + proto_h[idx], relu, * W2, reduce over n, sigmoid
    float b1v[4], w2v[4];
    #pragma unroll
    for (int ni = 0; ni < 4; ++ni) {
        int n = wave_n * 64 + ni * 16 + tid16;
        b1v[ni] = b1[n];
        w2v[ni] = W2[n];
    }
    #pragma unroll
    for (int mi = 0; mi < 4; ++mi) {
        #pragma unroll
        for (int r = 0; r < 4; ++r) {
            int m = wave_m * 64 + mi * 16 + quad * 4 + r;
            const float* ph = proto_h + (size_t)s_idx[m] * HIDDEN;
            float sum = 0.f;
            #pragma unroll
            for (int ni = 0; ni < 4; ++ni) {
                int n = wave_n * 64 + ni * 16 + tid16;
                float v = acc[mi][ni][r] + b1v[ni] + ph[n];
                sum += fmaxf(v, 0.f) * w2v[ni];
            }
            #pragma unroll
            for (int s = 1; s < 16; s <<= 1) sum += __shfl_xor(sum, s);
            if (tid16 == 0) s_red[m][wave_n] = sum;
        }
    }
    __syncthreads();
    if (t < 128) {
        float s = s_red[t][0] + s_red[t][1] + b2[0];
        out[q0 + t] = 1.f / (1.f + expf(-s));
    }
}

extern "C" void kernel_launch(void* const* d_in, const int* in_sizes, int n_in,
                              void* d_out, int out_size, void* d_ws, size_t ws_size,
                              hipStream_t stream) {
    const float* qf    = (const float*)d_in[0];   // [65536,1024]
    const float* proto = (const float*)d_in[1];   // [512,1024]
    const float* dist  = (const float*)d_in[2];   // [65536,512]
    const float* W1    = (const float*)d_in[3];   // [2048,128]
    const float* b1    = (const float*)d_in[4];   // [128]
    const float* W2    = (const float*)d_in[5];   // [128,1]
    const float* b2    = (const float*)d_in[6];   // [1]
    float* out = (float*)d_out;

    float* proto_h = (float*)d_ws;                                        // 256 KB
    unsigned short* w1t = (unsigned short*)((char*)d_ws + 512 * 128 * 4); // 256 KB

    prep_kernel<<<320, 256, 0, stream>>>(proto, W1, proto_h, w1t);

    int nq = in_sizes[0] / EMBED;  // 65536
    main_kernel<<<nq / 128, 256, 0, stream>>>(qf, dist, b1, W2, b2, proto_h, w1t, out);
}